// Round 6
// baseline (1009.623 us; speedup 1.0000x reference)
//
#include <hip/hip_runtime.h>
#include <hip/hip_bf16.h>

#define HID 128
#define ODIM 32

typedef short v8s  __attribute__((ext_vector_type(8)));
typedef float v4f  __attribute__((ext_vector_type(4)));
typedef float v16f __attribute__((ext_vector_type(16)));

__device__ __forceinline__ short f2bf(float f) {
    unsigned u = __builtin_bit_cast(unsigned, f);
    unsigned r = u + 0x7FFFu + ((u >> 16) & 1u);
    return (short)(r >> 16);
}
__device__ __forceinline__ float swishf(float v) {
    return __fdividef(v, 1.0f + __expf(-v));
}
__device__ __forceinline__ unsigned pk2(float a, float b) {
    __hip_bfloat162 p = __float22bfloat162_rn(make_float2(a, b));
    return *(unsigned*)&p;
}

__global__ void cvt_x(const float* __restrict__ x, uint2* __restrict__ xb, int n4) {
    int i = blockIdx.x * 256 + threadIdx.x;
    if (i < n4) {
        float4 f = ((const float4*)x)[i];
        uint2 r; r.x = pk2(f.x, f.y); r.y = pk2(f.z, f.w);
        xb[i] = r;
    }
}

// R6 = R4/R5 structure with the register-allocator occupancy target FIXED:
//   amdgpu_waves_per_eu(2,2) pins allocator at 2 waves/EU -> 256-reg unified
//   budget (LDS 83KB forces 1 block/CU = 2 waves/SIMD anyway, nothing lost).
//   xn prefetch registers deleted: xv is dead after L1's MFMAs, so the next
//   tile's x loads directly into xv there (same prefetch distance, -16 VGPRs).
template <bool USEBF>
__global__ void __launch_bounds__(512)
__attribute__((amdgpu_waves_per_eu(2, 2)))
subnet_mlp(const float* __restrict__ x, const ushort* __restrict__ xbf,
           const float* __restrict__ W1, const float* __restrict__ b1,
           const float* __restrict__ Wh, const float* __restrict__ bh,
           const float* __restrict__ Wo, const float* __restrict__ bo,
           float* __restrict__ out, int n_iters)
{
    __shared__ __align__(16) short sW1f[32 * 256];    // 16KB: chunk=(ct*4+s)*2+h
    __shared__ __align__(16) short sWhf[128 * 256];   // 64KB: chunk=((l*8+s)*4+ct)*2+h
    __shared__ __align__(16) float sB[3][HID];
    __shared__ __align__(16) float sWo[HID];

    const int tid = threadIdx.x;
    const int o   = blockIdx.x >> 3;
    const int blk = blockIdx.x & 7;

    // ---- one-time staging: weights -> bf16 fragment-major LDS ----
    for (int e = tid; e < 64 * HID; e += 512) {          // W1[o][k][c]
        int k = e >> 7, c = e & 127;
        int s = k >> 4, h = (k >> 3) & 1, j = k & 7, ct = c >> 5, col = c & 31;
        sW1f[((((ct << 2) + s) << 1 | h) << 8) + (col << 3) + j] =
            f2bf(W1[(o * 64 + k) * HID + c]);
    }
    #pragma unroll
    for (int l = 0; l < 2; ++l)
        for (int e = tid; e < HID * HID; e += 512) {     // Wh[l][o][k][c]
            int k = e >> 7, c = e & 127;
            int s = k >> 4, h = (k >> 3) & 1, j = k & 7, ct = c >> 5, col = c & 31;
            sWhf[(((((l << 3) + s) << 2 | ct) << 1 | h) << 8) + (col << 3) + j] =
                f2bf(Wh[((l * ODIM + o) * HID + k) * HID + c]);
        }
    if (tid < HID) {
        sB[0][tid] = b1[o * HID + tid];
        sB[1][tid] = bh[o * HID + tid];
        sB[2][tid] = bh[(ODIM + o) * HID + tid];
        sWo[tid]   = Wo[o * HID + tid];
    }
    __syncthreads();   // the ONLY barrier

    const int lane = tid & 63;
    const int h    = lane >> 5;   // wave half
    const int col  = lane & 31;   // x-row within tile / B n-index
    const int w    = tid >> 6;
    const float bov = bo[o];
    const int row0 = ((blk << 3) + w) * n_iters * 32;

    v8s xv[4];
    // B[k][col], k = s*16 + h*8 + j
    #pragma unroll
    for (int s = 0; s < 4; ++s) {
        if constexpr (USEBF) {
            xv[s] = *(const v8s*)&xbf[(size_t)(row0 + col) * 64 + s * 16 + h * 8];
        } else {
            const float* xp = x + (size_t)(row0 + col) * 64 + s * 16 + h * 8;
            float4 f0 = ((const float4*)xp)[0], f1 = ((const float4*)xp)[1];
            union { v8s v; unsigned u[4]; } cv;
            cv.u[0] = pk2(f0.x, f0.y); cv.u[1] = pk2(f0.z, f0.w);
            cv.u[2] = pk2(f1.x, f1.y); cv.u[3] = pk2(f1.z, f1.w);
            xv[s] = cv.v;
        }
    }

    for (int it = 0; it < n_iters; ++it) {
        const int base = row0 + it * 32;
        v16f acc[4];

        // ================= layer 1: 4 ct-tiles, K=64 =================
        #pragma unroll
        for (int ct = 0; ct < 4; ++ct)
            #pragma unroll
            for (int g = 0; g < 4; ++g) {
                v4f b = *(const v4f*)&sB[0][ct * 32 + g * 8 + h * 4];
                acc[ct][4*g+0] = b[0]; acc[ct][4*g+1] = b[1];
                acc[ct][4*g+2] = b[2]; acc[ct][4*g+3] = b[3];
            }
        #pragma unroll
        for (int s = 0; s < 4; ++s)
            #pragma unroll
            for (int ct = 0; ct < 4; ++ct) {
                v8s a = *(const v8s*)&sW1f[((((ct << 2) + s) << 1 | h) << 8) + (col << 3)];
                acc[ct] = __builtin_amdgcn_mfma_f32_32x32x16_bf16(a, xv[s], acc[ct], 0, 0, 0);
            }

        // xv is now dead -> reload it with the NEXT tile's x (prefetch, 0 extra regs)
        {
            const int nb = (it + 1 < n_iters) ? (base + 32) : row0;
            #pragma unroll
            for (int s = 0; s < 4; ++s) {
                if constexpr (USEBF) {
                    xv[s] = *(const v8s*)&xbf[(size_t)(nb + col) * 64 + s * 16 + h * 8];
                } else {
                    const float* xp = x + (size_t)(nb + col) * 64 + s * 16 + h * 8;
                    float4 f0 = ((const float4*)xp)[0], f1 = ((const float4*)xp)[1];
                    union { v8s v; unsigned u[4]; } cv;
                    cv.u[0] = pk2(f0.x, f0.y); cv.u[1] = pk2(f0.z, f0.w);
                    cv.u[2] = pk2(f1.x, f1.y); cv.u[3] = pk2(f1.z, f1.w);
                    xv[s] = cv.v;
                }
            }
        }

        v8s hb[8];

        // ---- boundary 1: per-cs swish + pack + intra-wave transpose ----
        #pragma unroll
        for (int cs = 0; cs < 4; ++cs) {
            unsigned pp[8];
            #pragma unroll
            for (int g = 0; g < 4; ++g) {
                pp[2*g]   = pk2(swishf(acc[cs][4*g+0]), swishf(acc[cs][4*g+1]));
                pp[2*g+1] = pk2(swishf(acc[cs][4*g+2]), swishf(acc[cs][4*g+3]));
            }
            #pragma unroll
            for (int hf = 0; hf < 2; ++hf) {
                unsigned a0 = pp[4*hf+0], a1 = pp[4*hf+1];
                unsigned b0 = pp[4*hf+2], b1 = pp[4*hf+3];
                unsigned sx = h ? a0 : b0, sy = h ? a1 : b1;
                unsigned rx = __shfl_xor(sx, 32, 64), ry = __shfl_xor(sy, 32, 64);
                union { v8s v; unsigned u[4]; } bb;
                bb.u[0] = h ? rx : a0;  bb.u[1] = h ? ry : a1;   // j0..3 (from half 0)
                bb.u[2] = h ? b0 : rx;  bb.u[3] = h ? b1 : ry;   // j4..7 (from half 1)
                hb[2*cs + hf] = bb.v;
            }
        }

        // ================= hidden layer 2: K=128 =================
        #pragma unroll
        for (int ct = 0; ct < 4; ++ct)
            #pragma unroll
            for (int g = 0; g < 4; ++g) {
                v4f b = *(const v4f*)&sB[1][ct * 32 + g * 8 + h * 4];
                acc[ct][4*g+0] = b[0]; acc[ct][4*g+1] = b[1];
                acc[ct][4*g+2] = b[2]; acc[ct][4*g+3] = b[3];
            }
        #pragma unroll
        for (int sp = 0; sp < 8; ++sp)
            #pragma unroll
            for (int ct = 0; ct < 4; ++ct) {
                v8s a = *(const v8s*)&sWhf[((((sp << 2) | ct) << 1 | h) << 8) + (col << 3)];
                acc[ct] = __builtin_amdgcn_mfma_f32_32x32x16_bf16(a, hb[sp], acc[ct], 0, 0, 0);
            }

        // ---- boundary 2 ----
        #pragma unroll
        for (int cs = 0; cs < 4; ++cs) {
            unsigned pp[8];
            #pragma unroll
            for (int g = 0; g < 4; ++g) {
                pp[2*g]   = pk2(swishf(acc[cs][4*g+0]), swishf(acc[cs][4*g+1]));
                pp[2*g+1] = pk2(swishf(acc[cs][4*g+2]), swishf(acc[cs][4*g+3]));
            }
            #pragma unroll
            for (int hf = 0; hf < 2; ++hf) {
                unsigned a0 = pp[4*hf+0], a1 = pp[4*hf+1];
                unsigned b0 = pp[4*hf+2], b1 = pp[4*hf+3];
                unsigned sx = h ? a0 : b0, sy = h ? a1 : b1;
                unsigned rx = __shfl_xor(sx, 32, 64), ry = __shfl_xor(sy, 32, 64);
                union { v8s v; unsigned u[4]; } bb;
                bb.u[0] = h ? rx : a0;  bb.u[1] = h ? ry : a1;
                bb.u[2] = h ? b0 : rx;  bb.u[3] = h ? b1 : ry;
                hb[2*cs + hf] = bb.v;
            }
        }

        // ================= hidden layer 3 + fused head =================
        #pragma unroll
        for (int ct = 0; ct < 4; ++ct)
            #pragma unroll
            for (int g = 0; g < 4; ++g) {
                v4f b = *(const v4f*)&sB[2][ct * 32 + g * 8 + h * 4];
                acc[ct][4*g+0] = b[0]; acc[ct][4*g+1] = b[1];
                acc[ct][4*g+2] = b[2]; acc[ct][4*g+3] = b[3];
            }
        #pragma unroll
        for (int sp = 0; sp < 8; ++sp)
            #pragma unroll
            for (int ct = 0; ct < 4; ++ct) {
                v8s a = *(const v8s*)&sWhf[(((((8 + sp) << 2) | ct) << 1 | h) << 8) + (col << 3)];
                acc[ct] = __builtin_amdgcn_mfma_f32_32x32x16_bf16(a, hb[sp], acc[ct], 0, 0, 0);
            }
        float p = 0.0f;
        #pragma unroll
        for (int ct = 0; ct < 4; ++ct)
            #pragma unroll
            for (int g = 0; g < 4; ++g) {
                v4f wo4 = *(const v4f*)&sWo[ct * 32 + g * 8 + h * 4];
                p += swishf(acc[ct][4*g+0]) * wo4[0];
                p += swishf(acc[ct][4*g+1]) * wo4[1];
                p += swishf(acc[ct][4*g+2]) * wo4[2];
                p += swishf(acc[ct][4*g+3]) * wo4[3];
            }
        p += __shfl_xor(p, 32, 64);
        if (h == 0)
            out[(size_t)(base + col) * ODIM + o] = p + bov;
    }
}

extern "C" void kernel_launch(void* const* d_in, const int* in_sizes, int n_in,
                              void* d_out, int out_size, void* d_ws, size_t ws_size,
                              hipStream_t stream) {
    const float* x  = (const float*)d_in[0];
    const float* W1 = (const float*)d_in[1];
    const float* b1 = (const float*)d_in[2];
    const float* Wh = (const float*)d_in[3];
    const float* bh = (const float*)d_in[4];
    const float* Wo = (const float*)d_in[5];
    const float* bo = (const float*)d_in[6];
    float* out = (float*)d_out;

    const int N = in_sizes[0] / 64;              // 32768
    const int n_iters = N / (8 * 8 * 32);        // 16 tiles of 32 rows per wave

    const size_t xb_bytes = (size_t)N * 64 * 2;
    dim3 grid(ODIM * 8);     // 256 blocks: 32 subnets x 8 row-slices, 1 per CU
    dim3 block(512);         // 8 waves = 2 per SIMD

    if (ws_size >= xb_bytes) {
        int n4 = N * 64 / 4;
        cvt_x<<<(n4 + 255) / 256, 256, 0, stream>>>(x, (uint2*)d_ws, n4);
        subnet_mlp<true><<<grid, block, 0, stream>>>(x, (const ushort*)d_ws,
                                                     W1, b1, Wh, bh, Wo, bo, out, n_iters);
    } else {
        subnet_mlp<false><<<grid, block, 0, stream>>>(x, nullptr,
                                                      W1, b1, Wh, bh, Wo, bo, out, n_iters);
    }
}

// Round 7
// 804.667 us; speedup vs baseline: 1.2547x; 1.2547x over previous
//
#include <hip/hip_runtime.h>
#include <hip/hip_bf16.h>

#define HID 128
#define ODIM 32

typedef short v8s  __attribute__((ext_vector_type(8)));
typedef float v4f  __attribute__((ext_vector_type(4)));
typedef float v16f __attribute__((ext_vector_type(16)));

__device__ __forceinline__ short f2bf(float f) {
    unsigned u = __builtin_bit_cast(unsigned, f);
    unsigned r = u + 0x7FFFu + ((u >> 16) & 1u);
    return (short)(r >> 16);
}
__device__ __forceinline__ float swishf(float v) {
    return __fdividef(v, 1.0f + __expf(-v));
}
__device__ __forceinline__ unsigned pk2(float a, float b) {
    __hip_bfloat162 p = __float22bfloat162_rn(make_float2(a, b));
    return *(unsigned*)&p;
}

__global__ void cvt_x(const float* __restrict__ x, uint2* __restrict__ xb, int n4) {
    int i = blockIdx.x * 256 + threadIdx.x;
    if (i < n4) {
        float4 f = ((const float4*)x)[i];
        uint2 r; r.x = pk2(f.x, f.y); r.y = pk2(f.z, f.w);
        xb[i] = r;
    }
}

// R7 = R4 structure with the live set cut to fit a 128-VGPR budget by
// construction (R4-R6 proved the allocator won't give more):
//   - B-frags built PER-SP inside the MFMA loop (hb: 32 regs -> 4)
//   - x prefetch moved to the head epilogue, where PP is dead
//   - transpose algebra identical to R4 (absmax-validated)
template <bool USEBF>
__global__ void __launch_bounds__(512)
subnet_mlp(const float* __restrict__ x, const ushort* __restrict__ xbf,
           const float* __restrict__ W1, const float* __restrict__ b1,
           const float* __restrict__ Wh, const float* __restrict__ bh,
           const float* __restrict__ Wo, const float* __restrict__ bo,
           float* __restrict__ out, int n_iters)
{
    __shared__ __align__(16) short sW1f[32 * 256];    // 16KB: chunk=(ct*4+s)*2+h
    __shared__ __align__(16) short sWhf[128 * 256];   // 64KB: chunk=((l*8+s)*4+ct)*2+h
    __shared__ __align__(16) float sB[3][HID];
    __shared__ __align__(16) float sWo[HID];

    const int tid = threadIdx.x;
    const int o   = blockIdx.x >> 3;
    const int blk = blockIdx.x & 7;

    // ---- one-time staging: weights -> bf16 fragment-major LDS ----
    for (int e = tid; e < 64 * HID; e += 512) {          // W1[o][k][c]
        int k = e >> 7, c = e & 127;
        int s = k >> 4, h = (k >> 3) & 1, j = k & 7, ct = c >> 5, col = c & 31;
        sW1f[((((ct << 2) + s) << 1 | h) << 8) + (col << 3) + j] =
            f2bf(W1[(o * 64 + k) * HID + c]);
    }
    #pragma unroll
    for (int l = 0; l < 2; ++l)
        for (int e = tid; e < HID * HID; e += 512) {     // Wh[l][o][k][c]
            int k = e >> 7, c = e & 127;
            int s = k >> 4, h = (k >> 3) & 1, j = k & 7, ct = c >> 5, col = c & 31;
            sWhf[(((((l << 3) + s) << 2 | ct) << 1 | h) << 8) + (col << 3) + j] =
                f2bf(Wh[((l * ODIM + o) * HID + k) * HID + c]);
        }
    if (tid < HID) {
        sB[0][tid] = b1[o * HID + tid];
        sB[1][tid] = bh[o * HID + tid];
        sB[2][tid] = bh[(ODIM + o) * HID + tid];
        sWo[tid]   = Wo[o * HID + tid];
    }
    __syncthreads();   // the ONLY barrier

    const int lane = tid & 63;
    const int h    = lane >> 5;   // wave half
    const int col  = lane & 31;   // x-row within tile / B n-index
    const int w    = tid >> 6;
    const float bov = bo[o];
    const int row0 = ((blk << 3) + w) * n_iters * 32;

    v8s xv[4];
    #pragma unroll
    for (int s = 0; s < 4; ++s) {               // B[k][col], k = s*16 + h*8 + j
        if constexpr (USEBF) {
            xv[s] = *(const v8s*)&xbf[(size_t)(row0 + col) * 64 + s * 16 + h * 8];
        } else {
            const float* xp = x + (size_t)(row0 + col) * 64 + s * 16 + h * 8;
            float4 f0 = ((const float4*)xp)[0], f1 = ((const float4*)xp)[1];
            union { v8s v; unsigned u[4]; } cv;
            cv.u[0] = pk2(f0.x, f0.y); cv.u[1] = pk2(f0.z, f0.w);
            cv.u[2] = pk2(f1.x, f1.y); cv.u[3] = pk2(f1.z, f1.w);
            xv[s] = cv.v;
        }
    }

    for (int it = 0; it < n_iters; ++it) {
        const int base = row0 + it * 32;
        v16f acc[4];
        unsigned PP[4][8];   // packed swish output: 4 cs-tiles x 8 uints (16 bf16)

        // ================= layer 1: 4 ct-tiles, K=64 =================
        #pragma unroll
        for (int ct = 0; ct < 4; ++ct)
            #pragma unroll
            for (int g = 0; g < 4; ++g) {
                v4f b = *(const v4f*)&sB[0][ct * 32 + g * 8 + h * 4];
                acc[ct][4*g+0] = b[0]; acc[ct][4*g+1] = b[1];
                acc[ct][4*g+2] = b[2]; acc[ct][4*g+3] = b[3];
            }
        #pragma unroll
        for (int s = 0; s < 4; ++s)
            #pragma unroll
            for (int ct = 0; ct < 4; ++ct) {
                v8s a = *(const v8s*)&sW1f[((((ct << 2) + s) << 1 | h) << 8) + (col << 3)];
                acc[ct] = __builtin_amdgcn_mfma_f32_32x32x16_bf16(a, xv[s], acc[ct], 0, 0, 0);
            }

        // ---- boundary 1: swish + pack (acc dies into PP) ----
        #pragma unroll
        for (int cs = 0; cs < 4; ++cs)
            #pragma unroll
            for (int g = 0; g < 4; ++g) {
                PP[cs][2*g]   = pk2(swishf(acc[cs][4*g+0]), swishf(acc[cs][4*g+1]));
                PP[cs][2*g+1] = pk2(swishf(acc[cs][4*g+2]), swishf(acc[cs][4*g+3]));
            }

        // ================= hidden layer 2: K=128, per-sp B-frag =================
        #pragma unroll
        for (int ct = 0; ct < 4; ++ct)
            #pragma unroll
            for (int g = 0; g < 4; ++g) {
                v4f b = *(const v4f*)&sB[1][ct * 32 + g * 8 + h * 4];
                acc[ct][4*g+0] = b[0]; acc[ct][4*g+1] = b[1];
                acc[ct][4*g+2] = b[2]; acc[ct][4*g+3] = b[3];
            }
        #pragma unroll
        for (int sp = 0; sp < 8; ++sp) {
            const int cs = sp >> 1, hf = sp & 1;
            unsigned a0 = PP[cs][4*hf+0], a1 = PP[cs][4*hf+1];
            unsigned b0 = PP[cs][4*hf+2], b1 = PP[cs][4*hf+3];
            unsigned sx = h ? a0 : b0, sy = h ? a1 : b1;
            unsigned rx = __shfl_xor(sx, 32, 64), ry = __shfl_xor(sy, 32, 64);
            union { v8s v; unsigned u[4]; } bb;
            bb.u[0] = h ? rx : a0;  bb.u[1] = h ? ry : a1;   // j0..3 (from half 0)
            bb.u[2] = h ? b0 : rx;  bb.u[3] = h ? b1 : ry;   // j4..7 (from half 1)
            #pragma unroll
            for (int ct = 0; ct < 4; ++ct) {
                v8s a = *(const v8s*)&sWhf[((((sp << 2) | ct) << 1 | h) << 8) + (col << 3)];
                acc[ct] = __builtin_amdgcn_mfma_f32_32x32x16_bf16(a, bb.v, acc[ct], 0, 0, 0);
            }
        }

        // ---- boundary 2 ----
        #pragma unroll
        for (int cs = 0; cs < 4; ++cs)
            #pragma unroll
            for (int g = 0; g < 4; ++g) {
                PP[cs][2*g]   = pk2(swishf(acc[cs][4*g+0]), swishf(acc[cs][4*g+1]));
                PP[cs][2*g+1] = pk2(swishf(acc[cs][4*g+2]), swishf(acc[cs][4*g+3]));
            }

        // ================= hidden layer 3: K=128, per-sp B-frag =================
        #pragma unroll
        for (int ct = 0; ct < 4; ++ct)
            #pragma unroll
            for (int g = 0; g < 4; ++g) {
                v4f b = *(const v4f*)&sB[2][ct * 32 + g * 8 + h * 4];
                acc[ct][4*g+0] = b[0]; acc[ct][4*g+1] = b[1];
                acc[ct][4*g+2] = b[2]; acc[ct][4*g+3] = b[3];
            }
        #pragma unroll
        for (int sp = 0; sp < 8; ++sp) {
            const int cs = sp >> 1, hf = sp & 1;
            unsigned a0 = PP[cs][4*hf+0], a1 = PP[cs][4*hf+1];
            unsigned b0 = PP[cs][4*hf+2], b1 = PP[cs][4*hf+3];
            unsigned sx = h ? a0 : b0, sy = h ? a1 : b1;
            unsigned rx = __shfl_xor(sx, 32, 64), ry = __shfl_xor(sy, 32, 64);
            union { v8s v; unsigned u[4]; } bb;
            bb.u[0] = h ? rx : a0;  bb.u[1] = h ? ry : a1;
            bb.u[2] = h ? b0 : rx;  bb.u[3] = h ? b1 : ry;
            #pragma unroll
            for (int ct = 0; ct < 4; ++ct) {
                v8s a = *(const v8s*)&sWhf[(((((8 + sp) << 2) | ct) << 1 | h) << 8) + (col << 3)];
                acc[ct] = __builtin_amdgcn_mfma_f32_32x32x16_bf16(a, bb.v, acc[ct], 0, 0, 0);
            }
        }

        // ================= fused head (PP dead -> room for x prefetch) =================
        {
            const int nb = (it + 1 < n_iters) ? (base + 32) : row0;
            #pragma unroll
            for (int s = 0; s < 4; ++s) {
                if constexpr (USEBF) {
                    xv[s] = *(const v8s*)&xbf[(size_t)(nb + col) * 64 + s * 16 + h * 8];
                } else {
                    const float* xp = x + (size_t)(nb + col) * 64 + s * 16 + h * 8;
                    float4 f0 = ((const float4*)xp)[0], f1 = ((const float4*)xp)[1];
                    union { v8s v; unsigned u[4]; } cv;
                    cv.u[0] = pk2(f0.x, f0.y); cv.u[1] = pk2(f0.z, f0.w);
                    cv.u[2] = pk2(f1.x, f1.y); cv.u[3] = pk2(f1.z, f1.w);
                    xv[s] = cv.v;
                }
            }
        }
        float p = 0.0f;
        #pragma unroll
        for (int ct = 0; ct < 4; ++ct)
            #pragma unroll
            for (int g = 0; g < 4; ++g) {
                v4f wo4 = *(const v4f*)&sWo[ct * 32 + g * 8 + h * 4];
                p += swishf(acc[ct][4*g+0]) * wo4[0];
                p += swishf(acc[ct][4*g+1]) * wo4[1];
                p += swishf(acc[ct][4*g+2]) * wo4[2];
                p += swishf(acc[ct][4*g+3]) * wo4[3];
            }
        p += __shfl_xor(p, 32, 64);
        if (h == 0)
            out[(size_t)(base + col) * ODIM + o] = p + bov;
    }
}

extern "C" void kernel_launch(void* const* d_in, const int* in_sizes, int n_in,
                              void* d_out, int out_size, void* d_ws, size_t ws_size,
                              hipStream_t stream) {
    const float* x  = (const float*)d_in[0];
    const float* W1 = (const float*)d_in[1];
    const float* b1 = (const float*)d_in[2];
    const float* Wh = (const float*)d_in[3];
    const float* bh = (const float*)d_in[4];
    const float* Wo = (const float*)d_in[5];
    const float* bo = (const float*)d_in[6];
    float* out = (float*)d_out;

    const int N = in_sizes[0] / 64;              // 32768
    const int n_iters = N / (8 * 8 * 32);        // 16 tiles of 32 rows per wave

    const size_t xb_bytes = (size_t)N * 64 * 2;
    dim3 grid(ODIM * 8);     // 256 blocks: 32 subnets x 8 row-slices, 1 per CU
    dim3 block(512);         // 8 waves = 2 per SIMD

    if (ws_size >= xb_bytes) {
        int n4 = N * 64 / 4;
        cvt_x<<<(n4 + 255) / 256, 256, 0, stream>>>(x, (uint2*)d_ws, n4);
        subnet_mlp<true><<<grid, block, 0, stream>>>(x, (const ushort*)d_ws,
                                                     W1, b1, Wh, bh, Wo, bo, out, n_iters);
    } else {
        subnet_mlp<false><<<grid, block, 0, stream>>>(x, nullptr,
                                                      W1, b1, Wh, bh, Wo, bo, out, n_iters);
    }
}